// Round 2
// baseline (217.235 us; speedup 1.0000x reference)
//
#include <hip/hip_runtime.h>

// Pink-noise 6-pole IIR as a two-kernel affine scan with perfectly coalesced
// memory access: each thread owns ONE float4 (4 consecutive samples), so lane
// stride is 16B. Cross-tile coupling via per-block affine offsets in d_ws.
//
// K1: per-block local scan -> block offset e_blk[6] (multiplier A^4096 is a
//     known constant, not stored).
// K2: recompute local scan, compose channel prefix from previous tiles' e_blk,
//     derive per-thread incoming state, run the 4 steps, write outputs.

constexpr int kL = 65536;          // samples per channel
constexpr int kThreads = 1024;     // 16 waves
constexpr int kWaves = kThreads / 64;
constexpr int kTile = kThreads * 4;        // 4096 samples per block
constexpr int kTilesPerCh = kL / kTile;    // 16

__device__ __constant__ float dA[6] = {0.99886f, 0.99332f, 0.969f, 0.8665f, 0.55f, -0.7616f};
__device__ __constant__ float dC[6] = {0.0555179f, 0.0750759f, 0.153852f, 0.3104856f, 0.5329522f, -0.016898f};

// ---------------- Kernel 1: per-block affine offset ----------------
__global__ __launch_bounds__(kThreads) void pink_pass1(
    const float* __restrict__ white, float* __restrict__ blk_e)
{
    const int tid  = threadIdx.x;
    const int lane = tid & 63;
    const int wave = tid >> 6;

    const size_t base = (size_t)blockIdx.x * kTile;
    float4 w4 = ((const float4*)(white + base))[tid];

    float e[6], m4[6];
    #pragma unroll
    for (int p = 0; p < 6; ++p) {
        const float A = dA[p], C = dC[p];
        float b = w4.x * C;
        b = fmaf(A, b, w4.y * C);
        b = fmaf(A, b, w4.z * C);
        b = fmaf(A, b, w4.w * C);
        e[p] = b;
        float a2 = A * A;
        m4[p] = a2 * a2;              // A^4
    }

    // Hillis-Steele inclusive scan over e; round-k multiplier is the
    // constant A^(4*2^k) for every updating lane (span is exactly 2^k).
    float mk[6];
    #pragma unroll
    for (int p = 0; p < 6; ++p) mk[p] = m4[p];
    #pragma unroll
    for (int k = 0; k < 6; ++k) {
        const int off = 1 << k;
        float fe[6];
        #pragma unroll
        for (int p = 0; p < 6; ++p) fe[p] = __shfl_up(e[p], off);
        if (lane >= off) {
            #pragma unroll
            for (int p = 0; p < 6; ++p) e[p] = fmaf(mk[p], fe[p], e[p]);
        }
        #pragma unroll
        for (int p = 0; p < 6; ++p) mk[p] *= mk[p];
    }

    __shared__ float se[kWaves][6];
    if (lane == 63) {
        #pragma unroll
        for (int p = 0; p < 6; ++p) se[wave][p] = e[p];
    }
    __syncthreads();

    if (tid < 6) {
        // M_WAVE = A^256 = (A^4)^(2^6)
        float Mw = m4[tid];
        #pragma unroll
        for (int s = 0; s < 6; ++s) Mw *= Mw;
        float E = 0.f;
        for (int w = 0; w < kWaves; ++w) E = fmaf(Mw, E, se[w][tid]);
        blk_e[(size_t)blockIdx.x * 6 + tid] = E;
    }
}

// ---------------- Kernel 2: apply prefix, produce outputs ----------------
__global__ __launch_bounds__(kThreads) void pink_pass2(
    const float* __restrict__ white, const float* __restrict__ blk_e,
    float* __restrict__ pink)
{
    constexpr float B6G = 0.115926f, DIRECT = 0.5362f, OUTG = 0.11f;

    const int tid  = threadIdx.x;
    const int lane = tid & 63;
    const int wave = tid >> 6;
    const int blk  = blockIdx.x;
    const int ch   = blk >> 4;          // kTilesPerCh == 16
    const int tile = blk & (kTilesPerCh - 1);

    const size_t base = (size_t)blk * kTile;
    float4 w4 = ((const float4*)(white + base))[tid];

    float e[6], m4[6];
    #pragma unroll
    for (int p = 0; p < 6; ++p) {
        const float A = dA[p], C = dC[p];
        float b = w4.x * C;
        b = fmaf(A, b, w4.y * C);
        b = fmaf(A, b, w4.z * C);
        b = fmaf(A, b, w4.w * C);
        e[p] = b;
        float a2 = A * A;
        m4[p] = a2 * a2;              // A^4
    }

    float mk[6];
    #pragma unroll
    for (int p = 0; p < 6; ++p) mk[p] = m4[p];
    #pragma unroll
    for (int k = 0; k < 6; ++k) {
        const int off = 1 << k;
        float fe[6];
        #pragma unroll
        for (int p = 0; p < 6; ++p) fe[p] = __shfl_up(e[p], off);
        if (lane >= off) {
            #pragma unroll
            for (int p = 0; p < 6; ++p) e[p] = fmaf(mk[p], fe[p], e[p]);
        }
        #pragma unroll
        for (int p = 0; p < 6; ++p) mk[p] *= mk[p];
    }

    // Exclusive e per lane.
    float ex[6];
    #pragma unroll
    for (int p = 0; p < 6; ++p) {
        ex[p] = __shfl_up(e[p], 1);
        if (lane == 0) ex[p] = 0.f;
    }

    __shared__ float se[kWaves][6];
    __shared__ float Tsh[6];
    if (lane == 63) {
        #pragma unroll
        for (int p = 0; p < 6; ++p) se[wave][p] = e[p];
    }
    __syncthreads();

    // Channel prefix from previous tiles: M_TILE = A^4096 = (A^4)^(2^10).
    if (tid < 6) {
        float Mt = m4[tid];
        #pragma unroll
        for (int s = 0; s < 10; ++s) Mt *= Mt;
        float T = 0.f;
        const float* ep = blk_e + (size_t)(ch * kTilesPerCh) * 6 + tid;
        for (int k = 0; k < tile; ++k) T = fmaf(Mt, T, ep[k * 6]);
        Tsh[tid] = T;
    }
    __syncthreads();

    // Wave incoming state: compose previous waves onto the tile prefix.
    float b[6];
    #pragma unroll
    for (int p = 0; p < 6; ++p) {
        float Mw = m4[p];
        #pragma unroll
        for (int s = 0; s < 6; ++s) Mw *= Mw;   // A^256
        float Wv = Tsh[p];
        for (int w2 = 0; w2 < wave; ++w2) Wv = fmaf(Mw, Wv, se[w2][p]);
        // Per-lane exclusive multiplier A^(4*lane) via bit product.
        float pm = 1.f, q = m4[p];
        #pragma unroll
        for (int bit = 0; bit < 6; ++bit) {
            if ((lane >> bit) & 1) pm *= q;
            q *= q;
        }
        b[p] = fmaf(pm, Wv, ex[p]);
    }

    // b6 = scaled previous white sample.
    float pw = __shfl_up(w4.w, 1);
    const size_t g0 = base + (size_t)tid * 4;
    if (lane == 0) pw = ((g0 & (size_t)(kL - 1)) == 0) ? 0.f : white[g0 - 1];
    float b6 = B6G * pw;

    auto step = [&](float w) -> float {
        #pragma unroll
        for (int p = 0; p < 6; ++p) b[p] = fmaf(dA[p], b[p], w * dC[p]);
        float s = ((b[0] + b[1]) + (b[2] + b[3])) + ((b[4] + b[5]) + b6);
        float pk = (s + DIRECT * w) * OUTG;
        b6 = B6G * w;
        return pk;
    };

    float4 o;
    o.x = step(w4.x);
    o.y = step(w4.y);
    o.z = step(w4.z);
    o.w = step(w4.w);
    ((float4*)(pink + base))[tid] = o;
}

extern "C" void kernel_launch(void* const* d_in, const int* in_sizes, int n_in,
                              void* d_out, int out_size, void* d_ws, size_t ws_size,
                              hipStream_t stream) {
    const float* white = (const float*)d_in[0];
    float* pink = (float*)d_out;
    float* blk_e = (float*)d_ws;              // nBlocks*6 floats (~98 KB)
    const int nBlocks = in_sizes[0] / kTile;  // 4096 for the reference shape

    hipLaunchKernelGGL(pink_pass1, dim3(nBlocks), dim3(kThreads), 0, stream,
                       white, blk_e);
    hipLaunchKernelGGL(pink_pass2, dim3(nBlocks), dim3(kThreads), 0, stream,
                       white, blk_e, pink);
}

// Round 3
// 151.837 us; speedup vs baseline: 1.4307x; 1.4307x over previous
//
#include <hip/hip_runtime.h>

// Pink-noise 6-pole IIR. Block = one channel (65536 samples), 512 threads.
// 8 double-buffered LDS stages of 8192 samples; per stage each thread scans
// 16 contiguous samples (affine scan for cross-thread coupling). Global
// access is fully coalesced (float4/lane); per-thread LDS access uses an XOR
// swizzle that keeps both access patterns bank-balanced. Barriers are
// lgkmcnt-only (s_barrier without the vmcnt drain of __syncthreads) so the
// next tile's global loads stay in flight across the compute phase.

constexpr int kL = 65536;
constexpr int kThreads = 512;
constexpr int kWaves = kThreads / 64;      // 8
constexpr int kStage = 8192;
constexpr int kStages = kL / kStage;       // 8
constexpr int kChunk = kStage / kThreads;  // 16
constexpr int kF4 = kStage / 4 / kThreads; // 4 float4 per thread (coalesced)

__device__ __forceinline__ int swz(int i) {
    // XOR bits [4:2] with bits [7:5]: bijective, preserves 16B alignment,
    // bank-balances both the 16-strided and the linear float4 patterns.
    return i ^ (((i >> 5) & 7) << 2);
}

__device__ __forceinline__ void wg_barrier() {
    // LDS-only barrier: drain lgkm (LDS) but leave global loads/stores in
    // flight (no vmcnt(0) drain like __syncthreads). All cross-thread data
    // in this kernel moves through LDS, so this is sufficient.
    asm volatile("s_waitcnt lgkmcnt(0)" ::: "memory");
    __builtin_amdgcn_s_barrier();
    asm volatile("" ::: "memory");
}

__global__ __launch_bounds__(kThreads) void pink_kernel(
    const float* __restrict__ white, float* __restrict__ pink)
{
    constexpr float A[6] = {0.99886f, 0.99332f, 0.969f, 0.8665f, 0.55f, -0.7616f};
    constexpr float C[6] = {0.0555179f, 0.0750759f, 0.153852f, 0.3104856f, 0.5329522f, -0.016898f};
    constexpr float B6G = 0.115926f, DIRECT = 0.5362f, OUTG = 0.11f;

    __shared__ __align__(16) float buf[2][kStage];  // 2 x 32 KB = 64 KB

    const int tid = threadIdx.x, lane = tid & 63, wave = tid >> 6;
    const float* __restrict__ wrow = white + (size_t)blockIdx.x * kL;
    float*       __restrict__ prow = pink  + (size_t)blockIdx.x * kL;

    // Per-pole constants: m16=A^16 (chunk), Mwv=A^1024 (wave span),
    // Mst=A^8192 (stage), pmL=A^(16*lane), pmW=Mwv^wave.
    float m16[6], Mwv[6], Mst[6], pmL[6], pmW[6];
    #pragma unroll
    for (int p = 0; p < 6; ++p) {
        float q = A[p];
        #pragma unroll
        for (int i = 0; i < 4; ++i) q *= q;      // A^16
        m16[p] = q;
        float pm = 1.f, qq = q;
        #pragma unroll
        for (int b = 0; b < 6; ++b) { if ((lane >> b) & 1) pm *= qq; qq *= qq; }
        pmL[p] = pm;
        float mw = q;
        #pragma unroll
        for (int i = 0; i < 6; ++i) mw *= mw;    // A^1024
        Mwv[p] = mw;
        float pv = 1.f, qw = mw;
        #pragma unroll
        for (int b = 0; b < 3; ++b) { if ((wave >> b) & 1) pv *= qw; qw *= qw; }
        pmW[p] = pv;
        Mst[p] = qw;                              // A^8192
    }

    float S[6];                                   // channel state entering stage
    #pragma unroll
    for (int p = 0; p < 6; ++p) S[p] = 0.f;

    // Prologue: stage 0 tile into buf[0].
    float4 nxt[kF4];
    {
        const float4* src = (const float4*)wrow;
        #pragma unroll
        for (int k = 0; k < kF4; ++k) nxt[k] = src[tid + k * kThreads];
        #pragma unroll
        for (int k = 0; k < kF4; ++k)
            *(float4*)&buf[0][swz(4 * (tid + k * kThreads))] = nxt[k];
    }

    for (int s = 0; s < kStages; ++s) {
        const int cur = s & 1, nb = cur ^ 1;

        // A: coalesced store of stage s-1 outputs (sitting in buf[nb]).
        if (s > 0) {
            float4 o[kF4];
            #pragma unroll
            for (int k = 0; k < kF4; ++k)
                o[k] = *(const float4*)&buf[nb][swz(4 * (tid + k * kThreads))];
            float4* dst = (float4*)(prow + (size_t)(s - 1) * kStage);
            #pragma unroll
            for (int k = 0; k < kF4; ++k) dst[tid + k * kThreads] = o[k];
        }
        // B: issue next tile's global loads (stay in flight through compute).
        if (s + 1 < kStages) {
            const float4* src = (const float4*)(wrow + (size_t)(s + 1) * kStage);
            #pragma unroll
            for (int k = 0; k < kF4; ++k) nxt[k] = src[tid + k * kThreads];
        }
        wg_barrier();  // buf[nb] store-reads done; buf[cur] tile visible

        // C: read my 16 samples + b6 source (before anyone overwrites).
        float w[kChunk];
        #pragma unroll
        for (int kk = 0; kk < kChunk / 4; ++kk) {
            float4 v = *(const float4*)&buf[cur][swz(kChunk * tid + 4 * kk)];
            w[4*kk] = v.x; w[4*kk+1] = v.y; w[4*kk+2] = v.z; w[4*kk+3] = v.w;
        }
        float pw;
        if (tid == 0) pw = (s == 0) ? 0.f : wrow[(size_t)s * kStage - 1];
        else          pw = buf[cur][swz(kChunk * tid - 1)];

        // Local scan from zero init.
        float e[6];
        #pragma unroll
        for (int p = 0; p < 6; ++p) e[p] = 0.f;
        #pragma unroll
        for (int k = 0; k < kChunk; ++k) {
            const float ww = w[k];
            #pragma unroll
            for (int p = 0; p < 6; ++p) e[p] = fmaf(A[p], e[p], ww * C[p]);
        }

        // Intra-wave affine scan (constant per-round multiplier).
        float mk[6];
        #pragma unroll
        for (int p = 0; p < 6; ++p) mk[p] = m16[p];
        #pragma unroll
        for (int r = 0; r < 6; ++r) {
            const int off = 1 << r;
            float fe[6];
            #pragma unroll
            for (int p = 0; p < 6; ++p) fe[p] = __shfl_up(e[p], off);
            if (lane >= off) {
                #pragma unroll
                for (int p = 0; p < 6; ++p) e[p] = fmaf(mk[p], fe[p], e[p]);
            }
            #pragma unroll
            for (int p = 0; p < 6; ++p) mk[p] *= mk[p];
        }
        float ex[6];
        #pragma unroll
        for (int p = 0; p < 6; ++p) {
            ex[p] = __shfl_up(e[p], 1);
            if (lane == 0) ex[p] = 0.f;
        }

        // Wave totals via scratch at the head of buf[nb] (contents already
        // consumed in phase A; next tile lands there only after sync3).
        float* seb = &buf[nb][0];   // layout [p][w2], 6 x 8 floats
        if (lane == 63) {
            #pragma unroll
            for (int p = 0; p < 6; ++p) seb[p * 8 + wave] = e[p];
        }
        wg_barrier();  // sync2: seb visible

        float P[6], Etot[6];
        #pragma unroll
        for (int p = 0; p < 6; ++p) {
            float4 lo = *(const float4*)&seb[p * 8];
            float4 hi = *(const float4*)&seb[p * 8 + 4];
            const float sv[8] = {lo.x, lo.y, lo.z, lo.w, hi.x, hi.y, hi.z, hi.w};
            float Pp = 0.f, Ep = 0.f;
            #pragma unroll
            for (int w2 = 0; w2 < kWaves; ++w2) {
                if (w2 < wave) Pp = fmaf(Mwv[p], Pp, sv[w2]);
                Ep = fmaf(Mwv[p], Ep, sv[w2]);
            }
            P[p] = Pp; Etot[p] = Ep;
        }

        // Incoming per-thread state; update channel state for next stage.
        float b[6];
        #pragma unroll
        for (int p = 0; p < 6; ++p) {
            const float PS = fmaf(pmW[p], S[p], P[p]);
            b[p] = fmaf(pmL[p], PS, ex[p]);
            S[p] = fmaf(Mst[p], S[p], Etot[p]);
        }
        float b6 = B6G * pw;

        wg_barrier();  // sync3: seb reads done before phase E overwrites buf[nb]

        // Recompute with correct init; outputs overwrite inputs in buf[cur].
        #pragma unroll
        for (int kk = 0; kk < kChunk / 4; ++kk) {
            float4 o;
            float* op = &o.x;
            #pragma unroll
            for (int j = 0; j < 4; ++j) {
                const float ww = w[4*kk + j];
                #pragma unroll
                for (int p = 0; p < 6; ++p) b[p] = fmaf(A[p], b[p], ww * C[p]);
                const float sum = ((b[0]+b[1]) + (b[2]+b[3])) + ((b[4]+b[5]) + b6);
                op[j] = fmaf(DIRECT, ww, sum) * OUTG;
                b6 = B6G * ww;
            }
            *(float4*)&buf[cur][swz(kChunk * tid + 4 * kk)] = o;
        }

        // E: write next tile into buf[nb].
        if (s + 1 < kStages) {
            #pragma unroll
            for (int k = 0; k < kF4; ++k)
                *(float4*)&buf[nb][swz(4 * (tid + k * kThreads))] = nxt[k];
        }
        wg_barrier();  // sync4: outputs + next tile visible for next iter
    }

    // Epilogue: store final stage's outputs.
    {
        const int lastb = (kStages - 1) & 1;
        float4* dst = (float4*)(prow + (size_t)(kStages - 1) * kStage);
        #pragma unroll
        for (int k = 0; k < kF4; ++k) {
            float4 o = *(const float4*)&buf[lastb][swz(4 * (tid + k * kThreads))];
            dst[tid + k * kThreads] = o;
        }
    }
}

extern "C" void kernel_launch(void* const* d_in, const int* in_sizes, int n_in,
                              void* d_out, int out_size, void* d_ws, size_t ws_size,
                              hipStream_t stream) {
    const float* white = (const float*)d_in[0];
    float* pink = (float*)d_out;
    const int B = in_sizes[0] / kL;   // 256 channels
    hipLaunchKernelGGL(pink_kernel, dim3(B), dim3(kThreads), 0, stream,
                       white, pink);
}

// Round 4
// 127.252 us; speedup vs baseline: 1.7071x; 1.1932x over previous
//
#include <hip/hip_runtime.h>

// Pink-noise 6-pole IIR, tile-parallel 3-kernel affine scan.
//   K1: per-tile (4096 samples) affine totals via scaled butterfly sum.
//   K2: per-channel exclusive scan over 16 tile totals (tiny).
//   K3: per-tile outputs: LDS-transposed coalesced IO, chunk=16 per thread,
//       wave affine scan, tile prefix preloaded (no serial global loop).

constexpr int kL = 65536;         // samples per channel
constexpr int kTile = 4096;       // samples per block
constexpr int kThr = 256;         // threads per block (4 waves)
constexpr int kChunk = 16;        // samples per thread
constexpr int kTilesPerCh = kL / kTile;  // 16

// XOR swizzle: bank-balances both the chunk-strided (16/thread) and the
// linear float4 access patterns; bijective on [0,4096); preserves 16B align.
__device__ __forceinline__ int swz(int i) {
    return i ^ (((i >> 5) & 7) << 2);
}

// ---------------- K1: per-tile affine totals ----------------
__global__ __launch_bounds__(kThr) void pink_tile_totals(
    const float* __restrict__ white, float* __restrict__ tile_e, int nTiles)
{
    constexpr float A[6] = {0.99886f, 0.99332f, 0.969f, 0.8665f, 0.55f, -0.7616f};
    constexpr float C[6] = {0.0555179f, 0.0750759f, 0.153852f, 0.3104856f, 0.5329522f, -0.016898f};

    __shared__ __align__(16) float buf[kTile];
    __shared__ float ssum[6][4];

    const int tid = threadIdx.x, lane = tid & 63, wave = tid >> 6;
    const int blk = blockIdx.x;

    const float4* src = (const float4*)(white + (size_t)blk * kTile);
    float4 v[4];
    #pragma unroll
    for (int k = 0; k < 4; ++k) v[k] = src[tid + k * kThr];
    #pragma unroll
    for (int k = 0; k < 4; ++k)
        *(float4*)&buf[swz(4 * (tid + k * kThr))] = v[k];

    // pmR[p] = (A^16)^(255 - tid): makes the block combine a plain sum.
    // (Underflow to 0 for fast poles is numerically correct: those
    // contributions are genuinely negligible.)
    float pmR[6];
    #pragma unroll
    for (int p = 0; p < 6; ++p) {
        float q = A[p];
        #pragma unroll
        for (int i = 0; i < 4; ++i) q *= q;      // A^16
        float pm = 1.f;
        const int r = 255 - tid;
        #pragma unroll
        for (int b = 0; b < 8; ++b) { if ((r >> b) & 1) pm *= q; q *= q; }
        pmR[p] = pm;
    }
    __syncthreads();

    float w[kChunk];
    #pragma unroll
    for (int kk = 0; kk < kChunk / 4; ++kk) {
        float4 x = *(const float4*)&buf[swz(kChunk * tid + 4 * kk)];
        w[4*kk] = x.x; w[4*kk+1] = x.y; w[4*kk+2] = x.z; w[4*kk+3] = x.w;
    }

    float e[6] = {0.f, 0.f, 0.f, 0.f, 0.f, 0.f};
    #pragma unroll
    for (int k = 0; k < kChunk; ++k) {
        const float ww = w[k];
        #pragma unroll
        for (int p = 0; p < 6; ++p) e[p] = fmaf(A[p], e[p], ww * C[p]);
    }
    #pragma unroll
    for (int p = 0; p < 6; ++p) e[p] *= pmR[p];

    // Butterfly sum across the wave (plain adds — already globally scaled).
    #pragma unroll
    for (int m = 1; m < 64; m <<= 1) {
        #pragma unroll
        for (int p = 0; p < 6; ++p) e[p] += __shfl_xor(e[p], m);
    }
    if (lane == 0) {
        #pragma unroll
        for (int p = 0; p < 6; ++p) ssum[p][wave] = e[p];
    }
    __syncthreads();
    if (tid < 6)
        tile_e[(size_t)tid * nTiles + blk] =
            ssum[tid][0] + ssum[tid][1] + ssum[tid][2] + ssum[tid][3];
}

// ---------------- K2: per-channel exclusive tile prefix ----------------
__global__ __launch_bounds__(256) void pink_tile_prefix(
    const float* __restrict__ tile_e, float* __restrict__ tile_P, int nTiles)
{
    constexpr float A[6] = {0.99886f, 0.99332f, 0.969f, 0.8665f, 0.55f, -0.7616f};
    const int p  = blockIdx.x;                       // pole 0..5
    const int ch = blockIdx.y * 256 + threadIdx.x;   // channel
    const int nCh = nTiles / kTilesPerCh;
    if (ch >= nCh) return;

    float Mt = A[p];
    #pragma unroll
    for (int i = 0; i < 12; ++i) Mt *= Mt;           // A^4096

    const float* ep = tile_e + (size_t)p * nTiles + (size_t)ch * kTilesPerCh;
    float*       Pp = tile_P + (size_t)p * nTiles + (size_t)ch * kTilesPerCh;
    float P = 0.f;
    #pragma unroll
    for (int t = 0; t < kTilesPerCh; ++t) {
        Pp[t] = P;
        P = fmaf(Mt, P, ep[t]);
    }
}

// ---------------- K3: per-tile outputs ----------------
__global__ __launch_bounds__(kThr) void pink_outputs(
    const float* __restrict__ white, const float* __restrict__ tile_P,
    float* __restrict__ pink, int nTiles)
{
    constexpr float A[6] = {0.99886f, 0.99332f, 0.969f, 0.8665f, 0.55f, -0.7616f};
    constexpr float C[6] = {0.0555179f, 0.0750759f, 0.153852f, 0.3104856f, 0.5329522f, -0.016898f};
    constexpr float B6G = 0.115926f, DIRECT = 0.5362f, OUTG = 0.11f;

    __shared__ __align__(16) float buf[kTile];
    __shared__ float swv[6][4];

    const int tid = threadIdx.x, lane = tid & 63, wave = tid >> 6;
    const int blk = blockIdx.x;
    const size_t base = (size_t)blk * kTile;

    // Tile incoming state (6 uniform scalar loads; no serial loop).
    float P[6];
    #pragma unroll
    for (int p = 0; p < 6; ++p) P[p] = tile_P[(size_t)p * nTiles + blk];

    // Previous white sample for thread 0's b6 (0 at channel start).
    float pw0 = 0.f;
    if (tid == 0 && (blk & (kTilesPerCh - 1)) != 0) pw0 = white[base - 1];

    const float4* src = (const float4*)(white + base);
    float4 v[4];
    #pragma unroll
    for (int k = 0; k < 4; ++k) v[k] = src[tid + k * kThr];
    #pragma unroll
    for (int k = 0; k < 4; ++k)
        *(float4*)&buf[swz(4 * (tid + k * kThr))] = v[k];

    // Constants: m16=A^16, pmL=(A^16)^lane, Mwv=A^1024.
    float m16[6], pmL[6], Mwv[6];
    #pragma unroll
    for (int p = 0; p < 6; ++p) {
        float q = A[p];
        #pragma unroll
        for (int i = 0; i < 4; ++i) q *= q;          // A^16
        m16[p] = q;
        float pm = 1.f, qq = q;
        #pragma unroll
        for (int b = 0; b < 6; ++b) { if ((lane >> b) & 1) pm *= qq; qq *= qq; }
        pmL[p] = pm;
        Mwv[p] = qq;                                  // (A^16)^64 = A^1024
    }
    __syncthreads();

    float w[kChunk];
    #pragma unroll
    for (int kk = 0; kk < kChunk / 4; ++kk) {
        float4 x = *(const float4*)&buf[swz(kChunk * tid + 4 * kk)];
        w[4*kk] = x.x; w[4*kk+1] = x.y; w[4*kk+2] = x.z; w[4*kk+3] = x.w;
    }
    const float pwl = (tid == 0) ? pw0 : buf[swz(kChunk * tid - 1)];

    // Local scan from zero init.
    float e[6] = {0.f, 0.f, 0.f, 0.f, 0.f, 0.f};
    #pragma unroll
    for (int k = 0; k < kChunk; ++k) {
        const float ww = w[k];
        #pragma unroll
        for (int p = 0; p < 6; ++p) e[p] = fmaf(A[p], e[p], ww * C[p]);
    }

    // Intra-wave affine scan (constant per-round multiplier).
    float mk[6];
    #pragma unroll
    for (int p = 0; p < 6; ++p) mk[p] = m16[p];
    #pragma unroll
    for (int r = 0; r < 6; ++r) {
        const int off = 1 << r;
        float fe[6];
        #pragma unroll
        for (int p = 0; p < 6; ++p) fe[p] = __shfl_up(e[p], off);
        if (lane >= off) {
            #pragma unroll
            for (int p = 0; p < 6; ++p) e[p] = fmaf(mk[p], fe[p], e[p]);
        }
        #pragma unroll
        for (int p = 0; p < 6; ++p) mk[p] *= mk[p];
    }
    float ex[6];
    #pragma unroll
    for (int p = 0; p < 6; ++p) {
        ex[p] = __shfl_up(e[p], 1);
        if (lane == 0) ex[p] = 0.f;
    }
    if (lane == 63) {
        #pragma unroll
        for (int p = 0; p < 6; ++p) swv[p][wave] = e[p];
    }
    __syncthreads();

    // Per-thread incoming state: fold tile prefix through previous waves,
    // then apply this lane's exclusive span.
    float b[6];
    #pragma unroll
    for (int p = 0; p < 6; ++p) {
        float X = P[p];
        #pragma unroll
        for (int w2 = 0; w2 < 3; ++w2)
            if (w2 < wave) X = fmaf(Mwv[p], X, swv[p][w2]);
        b[p] = fmaf(pmL[p], X, ex[p]);
    }
    float b6 = B6G * pwl;

    // Recompute with correct init; outputs overwrite inputs in buf.
    // (All reads of buf happened before the last barrier — safe.)
    #pragma unroll
    for (int kk = 0; kk < kChunk / 4; ++kk) {
        float4 o;
        float* op = &o.x;
        #pragma unroll
        for (int j = 0; j < 4; ++j) {
            const float ww = w[4*kk + j];
            #pragma unroll
            for (int p = 0; p < 6; ++p) b[p] = fmaf(A[p], b[p], ww * C[p]);
            const float sum = ((b[0]+b[1]) + (b[2]+b[3])) + ((b[4]+b[5]) + b6);
            op[j] = fmaf(DIRECT, ww, sum) * OUTG;
            b6 = B6G * ww;
        }
        *(float4*)&buf[swz(kChunk * tid + 4 * kk)] = o;
    }
    __syncthreads();

    float4* dst = (float4*)(pink + base);
    #pragma unroll
    for (int k = 0; k < 4; ++k)
        dst[tid + k * kThr] = *(const float4*)&buf[swz(4 * (tid + k * kThr))];
}

extern "C" void kernel_launch(void* const* d_in, const int* in_sizes, int n_in,
                              void* d_out, int out_size, void* d_ws, size_t ws_size,
                              hipStream_t stream) {
    const float* white = (const float*)d_in[0];
    float* pink = (float*)d_out;
    const int nTiles = in_sizes[0] / kTile;          // 4096
    const int nCh = nTiles / kTilesPerCh;            // 256
    float* tile_e = (float*)d_ws;                    // [6][nTiles]
    float* tile_P = tile_e + (size_t)6 * nTiles;     // [6][nTiles]

    hipLaunchKernelGGL(pink_tile_totals, dim3(nTiles), dim3(kThr), 0, stream,
                       white, tile_e, nTiles);
    hipLaunchKernelGGL(pink_tile_prefix, dim3(6, (nCh + 255) / 256), dim3(256),
                       0, stream, tile_e, tile_P, nTiles);
    hipLaunchKernelGGL(pink_outputs, dim3(nTiles), dim3(kThr), 0, stream,
                       white, tile_P, pink, nTiles);
}